// Round 1
// baseline (761.780 us; speedup 1.0000x reference)
//
#include <hip/hip_runtime.h>
#include <hip/hip_bf16.h>
#include <math.h>

// Problem constants (all compile-time from the reference):
// MUL=128, LS=0..4, DIM=3200, N=16384
// gathered layout: m-blocks of width C[m] = {640,1024,768,512,256}, offsets {0,640,1664,2432,2944}
#define N_ROWS 16384
#define DIM    3200

using short8  = __attribute__((ext_vector_type(8))) short;
using floatx4 = __attribute__((ext_vector_type(4))) float;

__device__ const int c_K [5] = {640, 1024, 768, 512, 256};
__device__ const int c_UO[5] = {0, 640, 1664, 2432, 2944};
__device__ const int c_WO[5] = {0, 409600, 1458176, 2048000, 2310144};
// 25 column tiles of width 128 across the 5 m-blocks
__device__ const int c_mOf[25]  = {0,0,0,0,0, 1,1,1,1,1,1,1,1, 2,2,2,2,2,2, 3,3,3,3, 4,4};
__device__ const int c_ntOf[25] = {0,1,2,3,4, 0,1,2,3,4,5,6,7, 0,1,2,3,4,5, 0,1,2,3, 0,1};

__device__ __forceinline__ constexpr int joff_of(int l) { return l==1 ? 0 : l==2 ? 9 : l==3 ? 34 : 83; }
__device__ __forceinline__ constexpr int gO(int m)      { return m==1 ? 640 : m==2 ? 1664 : m==3 ? 2432 : 2944; }

// ---------------------------------------------------------------------------
// Kernel 1: build J_l = expm(pi*(X0+X1)/sqrt(2)) in fp64, mirroring the numpy
// reference (order 24, 10 squarings). One block per l (l = blockIdx.x+1).
// ---------------------------------------------------------------------------
__global__ __launch_bounds__(128) void build_J(float* __restrict__ Jout)
{
    const int l = blockIdx.x + 1;
    const int d = 2*l + 1;
    const int dd = d*d;
    const int tid = threadIdx.x;
    __shared__ double Qr[81], Qi[81], Xr[81], Xi[81];
    __shared__ double M1r[81], M1i[81];
    __shared__ double Am[81], Em[81], Tm[81], Tn[81];

    if (tid == 0) {
        for (int e = 0; e < dd; ++e) { Qr[e]=0; Qi[e]=0; Xr[e]=0; Xi[e]=0; }
        const double jj = (double)l;
        for (int i = 0; i < d-1; ++i) {
            double mm = -jj + (double)i;                 // raising diag (k=-1)
            Xr[(i+1)*d + i] += 0.5 * (-sqrt(jj*(jj+1.0) - mm*(mm+1.0)));
            double m2 = -jj + 1.0 + (double)i;           // lowering diag (k=+1)
            Xr[i*d + (i+1)] += 0.5 * ( sqrt(jj*(jj+1.0) - m2*(m2-1.0)));
        }
        for (int i = 0; i < d; ++i) Xi[i*d + i] = -jj + (double)i;  // X1 = i*diag(m)
        const double is2 = 1.0 / sqrt(2.0);
        for (int mm = -l; mm < 0; ++mm) {
            int r = l + mm;
            Qr[r*d + (l - mm)] = is2;       // col l+|m|
            Qi[r*d + (l + mm)] = -is2;      // col l-|m|, value -i/sqrt2
        }
        Qr[l*d + l] = 1.0;
        for (int mm = 1; mm <= l; ++mm) {
            int r = l + mm;
            double sgn = (mm & 1) ? -1.0 : 1.0;
            Qr[r*d + (l + mm)] = sgn * is2;
            Qi[r*d + (l - mm)] = sgn * is2;
        }
        double fr, fi;                       // (-i)^l
        switch (l & 3) {
            case 0: fr = 1;  fi = 0;  break;
            case 1: fr = 0;  fi = -1; break;
            case 2: fr = -1; fi = 0;  break;
            default: fr = 0; fi = 1;  break;
        }
        for (int e = 0; e < dd; ++e) {
            double qr = Qr[e], qi = Qi[e];
            Qr[e] = qr*fr - qi*fi;
            Qi[e] = qr*fi + qi*fr;
        }
    }
    __syncthreads();
    const int i = (d > 0) ? tid / d : 0;
    const int j = (d > 0) ? tid % d : 0;
    if (tid < dd) {                          // M1 = X @ Q (complex)
        double ar = 0, ai = 0;
        for (int k = 0; k < d; ++k) {
            double xr = Xr[i*d+k], xi = Xi[i*d+k];
            double qr = Qr[k*d+j], qi = Qi[k*d+j];
            ar += xr*qr - xi*qi;
            ai += xr*qi + xi*qr;
        }
        M1r[tid] = ar; M1i[tid] = ai;
    }
    __syncthreads();
    if (tid < dd) {                          // A = Re(Q^H M1) * pi/sqrt2 / 2^10
        double ar = 0;
        for (int k = 0; k < d; ++k)
            ar += Qr[k*d+i]*M1r[k*d+j] + Qi[k*d+i]*M1i[k*d+j];
        const double scale = 3.14159265358979323846 / sqrt(2.0) / 1024.0;
        Am[tid] = ar * scale;
        Em[tid] = (i == j) ? 1.0 : 0.0;
        Tm[tid] = (i == j) ? 1.0 : 0.0;
    }
    __syncthreads();
    for (int k = 1; k < 24; ++k) {           // Taylor series
        if (tid < dd) {
            double s = 0;
            for (int b = 0; b < d; ++b) s += Tm[i*d+b] * Am[b*d+j];
            Tn[tid] = s / (double)k;
        }
        __syncthreads();
        if (tid < dd) { Tm[tid] = Tn[tid]; Em[tid] += Tn[tid]; }
        __syncthreads();
    }
    for (int s = 0; s < 10; ++s) {           // squarings
        if (tid < dd) {
            double v = 0;
            for (int b = 0; b < d; ++b) v += Em[i*d+b] * Em[b*d+j];
            Tn[tid] = v;
        }
        __syncthreads();
        if (tid < dd) Em[tid] = Tn[tid];
        __syncthreads();
    }
    if (tid < dd) Jout[joff_of(l) + tid] = (float)Em[tid];
}

// ---------------------------------------------------------------------------
// Kernel 2: build bf16 effective weights.
//   m=0: fc0_w (640x640) as-is.
//   m>=1: W_eff (2co x 2co) = [[A, -B],[B, A]] from w_m = [A;B] (2co x co),
//   so z = W_eff @ [u0;u1] reproduces re/im of the reference exactly.
// Stored row-major (N x K, K contiguous) for the BT GEMM.
// ---------------------------------------------------------------------------
__global__ __launch_bounds__(256) void prep_w(
    const float* __restrict__ fc0_w,
    const float* __restrict__ w1, const float* __restrict__ w2,
    const float* __restrict__ w3, const float* __restrict__ w4,
    __hip_bfloat16* __restrict__ Wall)
{
    const int m = blockIdx.y;
    const int idx = blockIdx.x * 256 + threadIdx.x;
    if (m == 0) {
        if (idx < 640*640) Wall[idx] = __float2bfloat16(fc0_w[idx]);
        return;
    }
    const int co = 128 * (5 - m);
    const int C  = 2 * co;
    if (idx >= C*C) return;
    const float* wm = (m==1) ? w1 : (m==2) ? w2 : (m==3) ? w3 : w4;
    const int jj = idx / C;
    const int tt = idx - jj * C;
    float v;
    if (jj < co) {
        v = (tt < co) ? wm[jj*co + tt] : -wm[(co + jj)*co + (tt - co)];
    } else {
        v = (tt < co) ? wm[jj*co + tt] :  wm[(jj - co)*co + (tt - co)];
    }
    Wall[c_WO[m] + idx] = __float2bfloat16(v);
}

// ---------------------------------------------------------------------------
// Rotation helpers: y = D^T v per (l,k) channel; gathered column mapping
// matches IDX[m] sorted order: channel p=(l-m)*128+k, entries (2p, 2p+1)
// for (l-m, l+m); m=0 block t = l*128+k.
// ---------------------------------------------------------------------------
template<int L>
__device__ __forceinline__ void rot_channel(const float* xs, const float* Dm,
                                            __hip_bfloat16* Urow, int k)
{
    constexpr int d = 2*L + 1;
    const float* Dl = Dm + joff_of(L);
    const int xoff = 128*L*L + k*d;
    float y[d];
#pragma unroll
    for (int q = 0; q < d; ++q) {
        float acc = 0.f;
#pragma unroll
        for (int j = 0; j < d; ++j) acc += Dl[j*d + q] * xs[xoff + j];
        y[q] = acc;
    }
#pragma unroll
    for (int q = 0; q < d; ++q) {
        const int mp = q - L;
        int g;
        if (mp == 0) g = L*128 + k;
        else {
            const int mm = mp < 0 ? -mp : mp;
            g = gO(mm) + 2*((L - mm)*128 + k) + (mp > 0 ? 1 : 0);
        }
        Urow[g] = __float2bfloat16(y[q]);
    }
}

template<int L>
__device__ __forceinline__ void unrot_channel(const __hip_bfloat16* ys, const float* Dm,
                                              float* orow, int k)
{
    constexpr int d = 2*L + 1;
    float yv[d];
#pragma unroll
    for (int q = 0; q < d; ++q) {
        const int mp = q - L;
        int g;
        if (mp == 0) g = L*128 + k;
        else {
            const int mm = mp < 0 ? -mp : mp;
            g = gO(mm) + 2*((L - mm)*128 + k) + (mp > 0 ? 1 : 0);
        }
        yv[q] = __bfloat162float(ys[g]);
    }
    const float* Dl = Dm + joff_of(L);
    const int ob = 128*L*L + k*d;
#pragma unroll
    for (int i = 0; i < d; ++i) {
        float acc = 0.f;
#pragma unroll
        for (int j = 0; j < d; ++j) acc += Dl[j*d + i] * yv[j];
        orow[ob + i] = acc;
    }
}

// ---------------------------------------------------------------------------
// Kernel 3: per-row D build + rotate + gather -> U (bf16, 16384x3200).
// One 256-thread block per row. D = Za @ (J @ Zb @ J), applied as D^T v.
// ---------------------------------------------------------------------------
__global__ __launch_bounds__(256) void rot_gather(
    const float* __restrict__ x, const float* __restrict__ R,
    const float* __restrict__ Jws, float* __restrict__ Dws,
    __hip_bfloat16* __restrict__ U)
{
    const int row = blockIdx.x;
    const int tid = threadIdx.x;
    __shared__ __align__(16) float xs[DIM];
    __shared__ __align__(16) __hip_bfloat16 Urow[DIM];
    __shared__ float Jl[164], Ptmp[164], Dm[164];
    __shared__ float cA[5], sA[5], cB[5], sB[5];

    // angles (all threads redundantly; broadcast loads)
    float r0 = R[row*3+0], r1 = R[row*3+1], r2 = R[row*3+2];
    float nrm = sqrtf(r0*r0 + r1*r1 + r2*r2);
    nrm = fmaxf(nrm, 1e-12f);
    float vx = r1/nrm, vy = r2/nrm, vz = r0/nrm;
    vx = fminf(1.f, fmaxf(-1.f, vx));
    vy = fminf(1.f, fmaxf(-1.f, vy));
    vz = fminf(1.f, fmaxf(-1.f, vz));
    float beta  = acosf(vy);
    float alpha = atan2f(vx, vz);

    if (tid < 164) Jl[tid] = Jws[tid];
    if (tid < 5) {
        float s, c;
        sincosf(alpha * (float)tid, &s, &c); sA[tid] = s; cA[tid] = c;
        sincosf(beta  * (float)tid, &s, &c); sB[tid] = s; cB[tid] = c;
    }
    {
        const float4* xg = (const float4*)(x + (size_t)row*DIM);
        float4* xl = (float4*)xs;
        for (int i = tid; i < DIM/4; i += 256) xl[i] = xg[i];
    }
    __syncthreads();

    int l = 0, base = 0;
    if (tid < 164) {                          // P = (J @ Zb) @ J
        if (tid < 9)       { l = 1; base = 0;  }
        else if (tid < 34) { l = 2; base = 9;  }
        else if (tid < 83) { l = 3; base = 34; }
        else               { l = 4; base = 83; }
        const int d = 2*l + 1;
        const int loc = tid - base;
        const int i = loc / d, j = loc - (loc/d)*d;
        const float* Jp = Jl + base;
        float acc = 0.f;
        for (int b = 0; b < d; ++b) {
            int f = l - b;
            float cb = cB[f < 0 ? -f : f];                       // cos((l-b)beta)
            float sb = (b >= l) ? sB[b-l] : -sB[l-b];            // sin((b-l)beta)
            acc += (Jp[i*d+b]*cb + Jp[i*d + (d-1-b)]*sb) * Jp[b*d+j];
        }
        Ptmp[tid] = acc;
    }
    __syncthreads();
    if (tid < 164) {                          // D = Za @ P
        const int d = 2*l + 1;
        const int loc = tid - base;
        const int i = loc / d, j = loc - (loc/d)*d;
        int f = l - i;
        float ca = cA[f < 0 ? -f : f];
        float sa = (f > 0) ? sA[f] : ((f < 0) ? -sA[-f] : 0.f);
        float v = ca * Ptmp[tid] + sa * Ptmp[base + (d-1-i)*d + j];
        Dm[tid] = v;
        Dws[(size_t)row*164 + tid] = v;       // reuse in second rotation
    }
    __syncthreads();

    for (int c = tid; c < 640; c += 256) {
        int ll = c >> 7, k = c & 127;
        switch (ll) {
            case 0: Urow[k] = __float2bfloat16(0.f); break;   // l=0 inputs dropped
            case 1: rot_channel<1>(xs, Dm, Urow, k); break;
            case 2: rot_channel<2>(xs, Dm, Urow, k); break;
            case 3: rot_channel<3>(xs, Dm, Urow, k); break;
            case 4: rot_channel<4>(xs, Dm, Urow, k); break;
        }
    }
    __syncthreads();
    {
        uint4* ug = (uint4*)(U + (size_t)row*DIM);
        const uint4* ul = (const uint4*)Urow;
        for (int i = tid; i < (DIM*2)/16; i += 256) ug[i] = ul[i];
    }
}

// ---------------------------------------------------------------------------
// Kernel 4: BT GEMM, Y[r, O+j] = sum_t U[r, O+t] * W[j, t] (+bias for m=0).
// 128x128 tile, BK=32, 4 waves (2x2 of 64x64), 16x16x32 bf16 MFMA,
// global_load_lds width-16 staging. grid = (128 Mtiles, 25 col tiles).
// ---------------------------------------------------------------------------
__device__ __forceinline__ void g2lds16(const void* g, void* l) {
    __builtin_amdgcn_global_load_lds(
        (const __attribute__((address_space(1))) void*)g,
        (__attribute__((address_space(3))) void*)l, 16, 0, 0);
}

__global__ __launch_bounds__(256) void gemm_bt(
    const __hip_bfloat16* __restrict__ U, const __hip_bfloat16* __restrict__ W,
    const float* __restrict__ bias, __hip_bfloat16* __restrict__ Y)
{
    const int by = blockIdx.y;
    const int m  = c_mOf[by];
    const int nt = c_ntOf[by];
    const int K  = c_K[m];
    const int row0 = blockIdx.x * 128;
    const __hip_bfloat16* Ablk = U + (size_t)row0*DIM + c_UO[m];
    const __hip_bfloat16* Bblk = W + c_WO[m] + (size_t)nt*128*K;
    __shared__ __align__(16) __hip_bfloat16 As[128*32];
    __shared__ __align__(16) __hip_bfloat16 Bs[128*32];
    const int tid  = threadIdx.x;
    const int lane = tid & 63, w = tid >> 6;
    const int frow = lane & 15, quad = lane >> 4;
    const int wm = (w >> 1)*64, wn = (w & 1)*64;

    floatx4 acc[4][4];
#pragma unroll
    for (int i = 0; i < 4; ++i)
#pragma unroll
        for (int j = 0; j < 4; ++j) acc[i][j] = (floatx4){0.f, 0.f, 0.f, 0.f};

    const int c1 = w*64 + lane;     // 16B chunk ids: chunk c -> LDS byte c*16,
    const int c2 = c1 + 256;        // i.e. row-major [row][k] with 64B rows.
    for (int k0 = 0; k0 < K; k0 += 32) {
        g2lds16(Ablk + (size_t)(c1 >> 2)*DIM + k0 + (c1 & 3)*8, (char*)As + w*1024);
        g2lds16(Ablk + (size_t)(c2 >> 2)*DIM + k0 + (c2 & 3)*8, (char*)As + 4096 + w*1024);
        g2lds16(Bblk + (size_t)(c1 >> 2)*K   + k0 + (c1 & 3)*8, (char*)Bs + w*1024);
        g2lds16(Bblk + (size_t)(c2 >> 2)*K   + k0 + (c2 & 3)*8, (char*)Bs + 4096 + w*1024);
        __syncthreads();
        short8 a[4], b[4];
#pragma unroll
        for (int t = 0; t < 4; ++t) {
            a[t] = *(const short8*)((const char*)As + (((wm + t*16 + frow)*32 + quad*8) * 2));
            b[t] = *(const short8*)((const char*)Bs + (((wn + t*16 + frow)*32 + quad*8) * 2));
        }
#pragma unroll
        for (int i = 0; i < 4; ++i)
#pragma unroll
            for (int j = 0; j < 4; ++j)
                acc[i][j] = __builtin_amdgcn_mfma_f32_16x16x32_bf16(a[i], b[j], acc[i][j], 0, 0, 0);
        __syncthreads();
    }
#pragma unroll
    for (int i = 0; i < 4; ++i) {
        const int r0 = row0 + wm + i*16 + quad*4;
#pragma unroll
        for (int j = 0; j < 4; ++j) {
            const int n = wn + j*16 + frow;
            const float bv = (m == 0) ? bias[nt*128 + n] : 0.f;
            const size_t colg = (size_t)c_UO[m] + nt*128 + n;
#pragma unroll
            for (int r = 0; r < 4; ++r)
                Y[(size_t)(r0 + r)*DIM + colg] = __float2bfloat16(acc[i][j][r] + bv);
        }
    }
}

// ---------------------------------------------------------------------------
// Kernel 5: un-gather + second rotation + fp32 store. One block per row.
// ---------------------------------------------------------------------------
__global__ __launch_bounds__(256) void ungather_rot(
    const __hip_bfloat16* __restrict__ Y, const float* __restrict__ Dws,
    float* __restrict__ out)
{
    const int row = blockIdx.x;
    const int tid = threadIdx.x;
    __shared__ __align__(16) __hip_bfloat16 ys[DIM];
    __shared__ __align__(16) float orow[DIM];
    __shared__ float Dm[164];
    {
        const uint4* yg = (const uint4*)(Y + (size_t)row*DIM);
        uint4* yl = (uint4*)ys;
        for (int i = tid; i < (DIM*2)/16; i += 256) yl[i] = yg[i];
    }
    if (tid < 164) Dm[tid] = Dws[(size_t)row*164 + tid];
    __syncthreads();
    for (int c = tid; c < 640; c += 256) {
        int ll = c >> 7, k = c & 127;
        switch (ll) {
            case 0: orow[k] = __bfloat162float(ys[k]); break;   // l=0 passthrough
            case 1: unrot_channel<1>(ys, Dm, orow, k); break;
            case 2: unrot_channel<2>(ys, Dm, orow, k); break;
            case 3: unrot_channel<3>(ys, Dm, orow, k); break;
            case 4: unrot_channel<4>(ys, Dm, orow, k); break;
        }
    }
    __syncthreads();
    {
        float4* og = (float4*)(out + (size_t)row*DIM);
        const float4* ol = (const float4*)orow;
        for (int i = tid; i < DIM/4; i += 256) og[i] = ol[i];
    }
}

// ---------------------------------------------------------------------------
extern "C" void kernel_launch(void* const* d_in, const int* in_sizes, int n_in,
                              void* d_out, int out_size, void* d_ws, size_t ws_size,
                              hipStream_t stream)
{
    (void)in_sizes; (void)n_in; (void)out_size; (void)ws_size;
    const float* x     = (const float*)d_in[0];
    const float* R     = (const float*)d_in[1];
    const float* fc0_w = (const float*)d_in[2];
    const float* fc0_b = (const float*)d_in[3];
    const float* w1    = (const float*)d_in[4];
    const float* w2    = (const float*)d_in[5];
    const float* w3    = (const float*)d_in[6];
    const float* w4    = (const float*)d_in[7];
    float* out = (float*)d_out;

    // workspace layout (bytes):
    //   J     @ 0           (656, padded to 1024)
    //   Wall  @ 1024        (2,375,680 bf16 = 4,751,360)
    //   Dws   @ 4,752,384   (16384*164 fp32 = 10,747,904)
    //   U     @ 15,500,288  (16384*3200 bf16 = 104,857,600)
    //   Y     @ 120,357,888 (16384*3200 bf16 = 104,857,600)  -> total 225,215,488
    char* ws = (char*)d_ws;
    float*          Jws  = (float*)ws;
    __hip_bfloat16* Wall = (__hip_bfloat16*)(ws + 1024);
    float*          Dws  = (float*)(ws + 4752384);
    __hip_bfloat16* U    = (__hip_bfloat16*)(ws + 15500288);
    __hip_bfloat16* Y    = (__hip_bfloat16*)(ws + 120357888);

    build_J    <<<dim3(4),        dim3(128), 0, stream>>>(Jws);
    prep_w     <<<dim3(4096, 5),  dim3(256), 0, stream>>>(fc0_w, w1, w2, w3, w4, Wall);
    rot_gather <<<dim3(N_ROWS),   dim3(256), 0, stream>>>(x, R, Jws, Dws, U);
    gemm_bt    <<<dim3(128, 25),  dim3(256), 0, stream>>>(U, Wall, fc0_b, Y);
    ungather_rot<<<dim3(N_ROWS),  dim3(256), 0, stream>>>(Y, Dws, out);
}

// Round 2
// 678.900 us; speedup vs baseline: 1.1221x; 1.1221x over previous
//
#include <hip/hip_runtime.h>
#include <hip/hip_bf16.h>
#include <math.h>

// Problem constants: MUL=128, LS=0..4, DIM=3200, N=16384
// gathered layout: m-blocks width C[m]={640,1024,768,512,256}, offsets {0,640,1664,2432,2944}
#define N_ROWS 16384
#define DIM    3200

using short8  = __attribute__((ext_vector_type(8))) short;
using floatx4 = __attribute__((ext_vector_type(4))) float;

__device__ const int c_K [5] = {640, 1024, 768, 512, 256};
__device__ const int c_UO[5] = {0, 640, 1664, 2432, 2944};
__device__ const int c_WO[5] = {0, 409600, 1458176, 2048000, 2310144};
// 25 column tiles of width 128 across the 5 m-blocks
__device__ const int c_mOf[25]  = {0,0,0,0,0, 1,1,1,1,1,1,1,1, 2,2,2,2,2,2, 3,3,3,3, 4,4};
__device__ const int c_ntOf[25] = {0,1,2,3,4, 0,1,2,3,4,5,6,7, 0,1,2,3,4,5, 0,1,2,3, 0,1};

__device__ __forceinline__ constexpr int joff_of(int l) { return l==1 ? 0 : l==2 ? 9 : l==3 ? 34 : 83; }
__device__ __forceinline__ constexpr int gO(int m)      { return m==1 ? 640 : m==2 ? 1664 : m==3 ? 2432 : 2944; }

// ---------------------------------------------------------------------------
// Kernel 1: build J_l = expm(pi*(X0+X1)/sqrt(2)) in fp64 (order 24, 10 sq).
// One block per l (l = blockIdx.x+1). Verified round 1.
// ---------------------------------------------------------------------------
__global__ __launch_bounds__(128) void build_J(float* __restrict__ Jout)
{
    const int l = blockIdx.x + 1;
    const int d = 2*l + 1;
    const int dd = d*d;
    const int tid = threadIdx.x;
    __shared__ double Qr[81], Qi[81], Xr[81], Xi[81];
    __shared__ double M1r[81], M1i[81];
    __shared__ double Am[81], Em[81], Tm[81], Tn[81];

    if (tid == 0) {
        for (int e = 0; e < dd; ++e) { Qr[e]=0; Qi[e]=0; Xr[e]=0; Xi[e]=0; }
        const double jj = (double)l;
        for (int i = 0; i < d-1; ++i) {
            double mm = -jj + (double)i;
            Xr[(i+1)*d + i] += 0.5 * (-sqrt(jj*(jj+1.0) - mm*(mm+1.0)));
            double m2 = -jj + 1.0 + (double)i;
            Xr[i*d + (i+1)] += 0.5 * ( sqrt(jj*(jj+1.0) - m2*(m2-1.0)));
        }
        for (int i = 0; i < d; ++i) Xi[i*d + i] = -jj + (double)i;
        const double is2 = 1.0 / sqrt(2.0);
        for (int mm = -l; mm < 0; ++mm) {
            int r = l + mm;
            Qr[r*d + (l - mm)] = is2;
            Qi[r*d + (l + mm)] = -is2;
        }
        Qr[l*d + l] = 1.0;
        for (int mm = 1; mm <= l; ++mm) {
            int r = l + mm;
            double sgn = (mm & 1) ? -1.0 : 1.0;
            Qr[r*d + (l + mm)] = sgn * is2;
            Qi[r*d + (l - mm)] = sgn * is2;
        }
        double fr, fi;                       // (-i)^l
        switch (l & 3) {
            case 0: fr = 1;  fi = 0;  break;
            case 1: fr = 0;  fi = -1; break;
            case 2: fr = -1; fi = 0;  break;
            default: fr = 0; fi = 1;  break;
        }
        for (int e = 0; e < dd; ++e) {
            double qr = Qr[e], qi = Qi[e];
            Qr[e] = qr*fr - qi*fi;
            Qi[e] = qr*fi + qi*fr;
        }
    }
    __syncthreads();
    const int i = tid / d;
    const int j = tid % d;
    if (tid < dd) {                          // M1 = X @ Q (complex)
        double ar = 0, ai = 0;
        for (int k = 0; k < d; ++k) {
            double xr = Xr[i*d+k], xi = Xi[i*d+k];
            double qr = Qr[k*d+j], qi = Qi[k*d+j];
            ar += xr*qr - xi*qi;
            ai += xr*qi + xi*qr;
        }
        M1r[tid] = ar; M1i[tid] = ai;
    }
    __syncthreads();
    if (tid < dd) {                          // A = Re(Q^H M1) * pi/sqrt2 / 2^10
        double ar = 0;
        for (int k = 0; k < d; ++k)
            ar += Qr[k*d+i]*M1r[k*d+j] + Qi[k*d+i]*M1i[k*d+j];
        const double scale = 3.14159265358979323846 / sqrt(2.0) / 1024.0;
        Am[tid] = ar * scale;
        Em[tid] = (i == j) ? 1.0 : 0.0;
        Tm[tid] = (i == j) ? 1.0 : 0.0;
    }
    __syncthreads();
    for (int k = 1; k < 24; ++k) {
        if (tid < dd) {
            double s = 0;
            for (int b = 0; b < d; ++b) s += Tm[i*d+b] * Am[b*d+j];
            Tn[tid] = s / (double)k;
        }
        __syncthreads();
        if (tid < dd) { Tm[tid] = Tn[tid]; Em[tid] += Tn[tid]; }
        __syncthreads();
    }
    for (int s = 0; s < 10; ++s) {
        if (tid < dd) {
            double v = 0;
            for (int b = 0; b < d; ++b) v += Em[i*d+b] * Em[b*d+j];
            Tn[tid] = v;
        }
        __syncthreads();
        if (tid < dd) Em[tid] = Tn[tid];
        __syncthreads();
    }
    if (tid < dd) Jout[joff_of(l) + tid] = (float)Em[tid];
}

// ---------------------------------------------------------------------------
// Kernel 2: bf16 effective weights (verified round 1).
// ---------------------------------------------------------------------------
__global__ __launch_bounds__(256) void prep_w(
    const float* __restrict__ fc0_w,
    const float* __restrict__ w1, const float* __restrict__ w2,
    const float* __restrict__ w3, const float* __restrict__ w4,
    __hip_bfloat16* __restrict__ Wall)
{
    const int m = blockIdx.y;
    const int idx = blockIdx.x * 256 + threadIdx.x;
    if (m == 0) {
        if (idx < 640*640) Wall[idx] = __float2bfloat16(fc0_w[idx]);
        return;
    }
    const int co = 128 * (5 - m);
    const int C  = 2 * co;
    if (idx >= C*C) return;
    const float* wm = (m==1) ? w1 : (m==2) ? w2 : (m==3) ? w3 : w4;
    const int jj = idx / C;
    const int tt = idx - jj * C;
    float v;
    if (jj < co) {
        v = (tt < co) ? wm[jj*co + tt] : -wm[(co + jj)*co + (tt - co)];
    } else {
        v = (tt < co) ? wm[jj*co + tt] :  wm[(jj - co)*co + (tt - co)];
    }
    Wall[c_WO[m] + idx] = __float2bfloat16(v);
}

// ---------------------------------------------------------------------------
// Kernel 3a: per-row trig table. trig[row*20 + {0..4:cA, 5..9:sA, 10..14:cB, 15..19:sB}]
// ---------------------------------------------------------------------------
__global__ __launch_bounds__(256) void build_trig(
    const float* __restrict__ R, float* __restrict__ trig)
{
    const int row = blockIdx.x * 256 + threadIdx.x;
    if (row >= N_ROWS) return;
    float r0 = R[row*3+0], r1 = R[row*3+1], r2 = R[row*3+2];
    float nrm = sqrtf(r0*r0 + r1*r1 + r2*r2);
    nrm = fmaxf(nrm, 1e-12f);
    float vx = r1/nrm, vy = r2/nrm, vz = r0/nrm;
    vx = fminf(1.f, fmaxf(-1.f, vx));
    vy = fminf(1.f, fmaxf(-1.f, vy));
    vz = fminf(1.f, fmaxf(-1.f, vz));
    float beta  = acosf(vy);
    float alpha = atan2f(vx, vz);
    float* t = trig + row*20;
#pragma unroll
    for (int m = 0; m < 5; ++m) {
        float s, c;
        sincosf(alpha * (float)m, &s, &c);
        t[m] = c; t[5+m] = s;
        sincosf(beta * (float)m, &s, &c);
        t[10+m] = c; t[15+m] = s;
    }
}

// ---------------------------------------------------------------------------
// Kernel 3b: D matrices, thread per (row, entry). D = Za @ ((J Zb) J).
// Formulas identical to verified round-1 in-block build.
// ---------------------------------------------------------------------------
__global__ __launch_bounds__(256) void build_D(
    const float* __restrict__ Jws, const float* __restrict__ trig,
    float* __restrict__ Dws)
{
    const int gid = blockIdx.x * 256 + threadIdx.x;
    if (gid >= N_ROWS * 164) return;
    const int row = gid / 164;
    const int e   = gid - row * 164;
    int l, base;
    if (e < 9)       { l = 1; base = 0;  }
    else if (e < 34) { l = 2; base = 9;  }
    else if (e < 83) { l = 3; base = 34; }
    else             { l = 4; base = 83; }
    const int d = 2*l + 1;
    const int loc = e - base;
    const int i = loc / d, j = loc - i*d;
    const float* Jp = Jws + base;
    const float* t  = trig + row*20;
    float pij = 0.f, pdj = 0.f;
    for (int b = 0; b < d; ++b) {
        int f = l - b; int af = f < 0 ? -f : f;
        float cb = t[10 + af];
        float sb = (b >= l) ? t[15 + b - l] : -t[15 + l - b];
        float zr  = Jp[i*d + b]*cb + Jp[i*d + (d-1-b)]*sb;
        float zr2 = Jp[(d-1-i)*d + b]*cb + Jp[(d-1-i)*d + (d-1-b)]*sb;
        float jb  = Jp[b*d + j];
        pij += zr  * jb;
        pdj += zr2 * jb;
    }
    int f = l - i; int af = f < 0 ? -f : f;
    float ca = t[af];
    float sa = (f > 0) ? t[5 + f] : ((f < 0) ? -t[5 + af] : 0.f);
    Dws[gid] = ca * pij + sa * pdj;
}

// ---------------------------------------------------------------------------
// Rotation channel helpers (no LDS; packed 4B writes/reads for the +/-m pairs)
// ---------------------------------------------------------------------------
template<int L>
__device__ __forceinline__ void rot_one(const float* __restrict__ xr,
                                        const float* __restrict__ Dl,
                                        __hip_bfloat16* __restrict__ Urow, int k)
{
    constexpr int d = 2*L + 1;
    float xv[d], y[d];
    const float* xp = xr + 128*L*L + k*d;
#pragma unroll
    for (int j = 0; j < d; ++j) xv[j] = xp[j];
#pragma unroll
    for (int q = 0; q < d; ++q) {
        float acc = 0.f;
#pragma unroll
        for (int j = 0; j < d; ++j) acc += Dl[j*d + q] * xv[j];
        y[q] = acc;
    }
    Urow[L*128 + k] = __float2bfloat16(y[L]);            // m=0
#pragma unroll
    for (int m = 1; m <= L; ++m) {                        // (-m,+m) pair -> one 4B store
        unsigned short lo = __builtin_bit_cast(unsigned short, __float2bfloat16(y[L-m]));
        unsigned short hi = __builtin_bit_cast(unsigned short, __float2bfloat16(y[L+m]));
        unsigned int pack = ((unsigned int)hi << 16) | lo;
        *(unsigned int*)(Urow + gO(m) + 2*((L-m)*128 + k)) = pack;
    }
}

template<int L>
__device__ __forceinline__ void unrot_one(const __hip_bfloat16* __restrict__ Yrow,
                                          const float* __restrict__ Dl,
                                          float* __restrict__ orow, int k)
{
    constexpr int d = 2*L + 1;
    float yv[d];
    yv[L] = __bfloat162float(Yrow[L*128 + k]);
#pragma unroll
    for (int m = 1; m <= L; ++m) {
        unsigned int pack = *(const unsigned int*)(Yrow + gO(m) + 2*((L-m)*128 + k));
        unsigned short lo = (unsigned short)(pack & 0xffffu);
        unsigned short hi = (unsigned short)(pack >> 16);
        yv[L-m] = __bfloat162float(__builtin_bit_cast(__hip_bfloat16, lo));
        yv[L+m] = __bfloat162float(__builtin_bit_cast(__hip_bfloat16, hi));
    }
    float* op = orow + 128*L*L + k*d;
#pragma unroll
    for (int i = 0; i < d; ++i) {
        float acc = 0.f;
#pragma unroll
        for (int j = 0; j < d; ++j) acc += Dl[j*d + i] * yv[j];
        op[i] = acc;
    }
}

// ---------------------------------------------------------------------------
// Kernel 4: rotate+gather, thread per (row, channel). 640 = 5*128 channels/row
// so waves never straddle rows and l is wave-uniform. No LDS, no barriers.
// ---------------------------------------------------------------------------
__global__ __launch_bounds__(256) void rot_gather(
    const float* __restrict__ x, const float* __restrict__ Dws,
    __hip_bfloat16* __restrict__ U)
{
    const int gid = blockIdx.x * 256 + threadIdx.x;
    const int row = gid / 640;
    const int c   = gid - row * 640;
    const int l = c >> 7, k = c & 127;
    const float* xr = x + (size_t)row * DIM;
    __hip_bfloat16* Urow = U + (size_t)row * DIM;
    const float* Dm = Dws + (size_t)row * 164;
    switch (l) {
        case 0: Urow[k] = __float2bfloat16(0.f); break;   // l=0 inputs dropped
        case 1: rot_one<1>(xr, Dm + 0,  Urow, k); break;
        case 2: rot_one<2>(xr, Dm + 9,  Urow, k); break;
        case 3: rot_one<3>(xr, Dm + 34, Urow, k); break;
        case 4: rot_one<4>(xr, Dm + 83, Urow, k); break;
    }
}

// ---------------------------------------------------------------------------
// Kernel 5: BT GEMM (verified round 1). Y[r,O+j] = sum_t U[r,O+t]*W[j,t] (+bias m=0)
// ---------------------------------------------------------------------------
__device__ __forceinline__ void g2lds16(const void* g, void* l) {
    __builtin_amdgcn_global_load_lds(
        (const __attribute__((address_space(1))) void*)g,
        (__attribute__((address_space(3))) void*)l, 16, 0, 0);
}

__global__ __launch_bounds__(256) void gemm_bt(
    const __hip_bfloat16* __restrict__ U, const __hip_bfloat16* __restrict__ W,
    const float* __restrict__ bias, __hip_bfloat16* __restrict__ Y)
{
    const int by = blockIdx.y;
    const int m  = c_mOf[by];
    const int nt = c_ntOf[by];
    const int K  = c_K[m];
    const int row0 = blockIdx.x * 128;
    const __hip_bfloat16* Ablk = U + (size_t)row0*DIM + c_UO[m];
    const __hip_bfloat16* Bblk = W + c_WO[m] + (size_t)nt*128*K;
    __shared__ __align__(16) __hip_bfloat16 As[128*32];
    __shared__ __align__(16) __hip_bfloat16 Bs[128*32];
    const int tid  = threadIdx.x;
    const int lane = tid & 63, w = tid >> 6;
    const int frow = lane & 15, quad = lane >> 4;
    const int wm = (w >> 1)*64, wn = (w & 1)*64;

    floatx4 acc[4][4];
#pragma unroll
    for (int i = 0; i < 4; ++i)
#pragma unroll
        for (int j = 0; j < 4; ++j) acc[i][j] = (floatx4){0.f, 0.f, 0.f, 0.f};

    const int c1 = w*64 + lane;
    const int c2 = c1 + 256;
    for (int k0 = 0; k0 < K; k0 += 32) {
        g2lds16(Ablk + (size_t)(c1 >> 2)*DIM + k0 + (c1 & 3)*8, (char*)As + w*1024);
        g2lds16(Ablk + (size_t)(c2 >> 2)*DIM + k0 + (c2 & 3)*8, (char*)As + 4096 + w*1024);
        g2lds16(Bblk + (size_t)(c1 >> 2)*K   + k0 + (c1 & 3)*8, (char*)Bs + w*1024);
        g2lds16(Bblk + (size_t)(c2 >> 2)*K   + k0 + (c2 & 3)*8, (char*)Bs + 4096 + w*1024);
        __syncthreads();
        short8 a[4], b[4];
#pragma unroll
        for (int t = 0; t < 4; ++t) {
            a[t] = *(const short8*)((const char*)As + (((wm + t*16 + frow)*32 + quad*8) * 2));
            b[t] = *(const short8*)((const char*)Bs + (((wn + t*16 + frow)*32 + quad*8) * 2));
        }
#pragma unroll
        for (int i = 0; i < 4; ++i)
#pragma unroll
            for (int j = 0; j < 4; ++j)
                acc[i][j] = __builtin_amdgcn_mfma_f32_16x16x32_bf16(a[i], b[j], acc[i][j], 0, 0, 0);
        __syncthreads();
    }
#pragma unroll
    for (int i = 0; i < 4; ++i) {
        const int r0 = row0 + wm + i*16 + quad*4;
#pragma unroll
        for (int j = 0; j < 4; ++j) {
            const int n = wn + j*16 + frow;
            const float bv = (m == 0) ? bias[nt*128 + n] : 0.f;
            const size_t colg = (size_t)c_UO[m] + nt*128 + n;
#pragma unroll
            for (int r = 0; r < 4; ++r)
                Y[(size_t)(r0 + r)*DIM + colg] = __float2bfloat16(acc[i][j][r] + bv);
        }
    }
}

// ---------------------------------------------------------------------------
// Kernel 6: un-gather + second rotation + fp32 store. Thread per (row,channel).
// ---------------------------------------------------------------------------
__global__ __launch_bounds__(256) void ungather_rot(
    const __hip_bfloat16* __restrict__ Y, const float* __restrict__ Dws,
    float* __restrict__ out)
{
    const int gid = blockIdx.x * 256 + threadIdx.x;
    const int row = gid / 640;
    const int c   = gid - row * 640;
    const int l = c >> 7, k = c & 127;
    const __hip_bfloat16* Yrow = Y + (size_t)row * DIM;
    float* orow = out + (size_t)row * DIM;
    const float* Dm = Dws + (size_t)row * 164;
    switch (l) {
        case 0: orow[k] = __bfloat162float(Yrow[k]); break;   // l=0 passthrough
        case 1: unrot_one<1>(Yrow, Dm + 0,  orow, k); break;
        case 2: unrot_one<2>(Yrow, Dm + 9,  orow, k); break;
        case 3: unrot_one<3>(Yrow, Dm + 34, orow, k); break;
        case 4: unrot_one<4>(Yrow, Dm + 83, orow, k); break;
    }
}

// ---------------------------------------------------------------------------
extern "C" void kernel_launch(void* const* d_in, const int* in_sizes, int n_in,
                              void* d_out, int out_size, void* d_ws, size_t ws_size,
                              hipStream_t stream)
{
    (void)in_sizes; (void)n_in; (void)out_size; (void)ws_size;
    const float* x     = (const float*)d_in[0];
    const float* R     = (const float*)d_in[1];
    const float* fc0_w = (const float*)d_in[2];
    const float* fc0_b = (const float*)d_in[3];
    const float* w1    = (const float*)d_in[4];
    const float* w2    = (const float*)d_in[5];
    const float* w3    = (const float*)d_in[6];
    const float* w4    = (const float*)d_in[7];
    float* out = (float*)d_out;

    // workspace layout (bytes):
    //   J     @ 0           (656, padded to 1024)
    //   Wall  @ 1024        (4,751,360)
    //   Dws   @ 4,752,384   (10,747,904)
    //   U     @ 15,500,288  (104,857,600)
    //   Y     @ 120,357,888 (104,857,600)  -> total 225,215,488
    //   trig aliased onto Y's first 1.31 MB (dead before gemm writes Y)
    char* ws = (char*)d_ws;
    float*          Jws  = (float*)ws;
    __hip_bfloat16* Wall = (__hip_bfloat16*)(ws + 1024);
    float*          Dws  = (float*)(ws + 4752384);
    __hip_bfloat16* U    = (__hip_bfloat16*)(ws + 15500288);
    __hip_bfloat16* Y    = (__hip_bfloat16*)(ws + 120357888);
    float*          trig = (float*)(ws + 120357888);   // alias, see above

    build_J     <<<dim3(4),         dim3(128), 0, stream>>>(Jws);
    prep_w      <<<dim3(4096, 5),   dim3(256), 0, stream>>>(fc0_w, w1, w2, w3, w4, Wall);
    build_trig  <<<dim3(64),        dim3(256), 0, stream>>>(R, trig);
    build_D     <<<dim3(10496),     dim3(256), 0, stream>>>(Jws, trig, Dws);
    rot_gather  <<<dim3(40960),     dim3(256), 0, stream>>>(x, Dws, U);
    gemm_bt     <<<dim3(128, 25),   dim3(256), 0, stream>>>(U, Wall, fc0_b, Y);
    ungather_rot<<<dim3(40960),     dim3(256), 0, stream>>>(Y, Dws, out);
}